// Round 5
// baseline (1436.484 us; speedup 1.0000x reference)
//
#include <hip/hip_runtime.h>

#define NTHREADS 256
#define NB 4        // nodes per block (N=50000 -> 12500 blocks, no tail)
#define K 16
#define KP1 17
#define F 128
#define H 8
#define D 64
#define FP 132      // padded xall row stride; 2-way max bank alias = free
#define ATP 20      // attnT row stride (17 used), 16B-aligned rows
#define NEG_SLOPE 0.2f

// LDS: xall 4*17*132*4 = 35904 + attnT 4*8*20*4 = 2560 + self 128 = 38592 B -> 4 blocks/CU
// VGPR target ~110: __launch_bounds__(256,4) allows 128 (4 waves/SIMD, 16 waves/CU).
// Round-4 structure (proven 383us). Changes: P5 explicit next-fb W prefetch (reg double
// buffer, fb unrolled) to hide L2 latency; attn stored transposed [nb][h][k] so P2 writes
// float2, P3 is 4xfloat4 in-register, P4 attn reads are b128 (was 68 scalar b32).

__global__ __launch_bounds__(NTHREADS, 4) void gat_kernel(
    const float* __restrict__ x_self,   // [N,F]
    const float* __restrict__ x_neigh,  // [N,K,F]
    const float* __restrict__ W,        // [H,F,D]
    const float* __restrict__ a_self,   // [H,F]
    const float* __restrict__ a_neigh,  // [H,F]
    float* __restrict__ out,            // [N,H*D]
    int N)
{
    __shared__ __align__(16) float xall[NB][KP1][FP];   // k=0 is self row; reused as yb after phase 4
    __shared__ __align__(16) float attnT[NB][H][ATP];   // [node][head][k] transposed
    __shared__ float self_s[NB][H];

    float* yb = (float*)xall;   // [NB][H][F] alias (stride F), valid after phase-4 second sync

    const int tid = threadIdx.x;
    const int node0 = blockIdx.x * NB;

    // ---- Phase 1: stage x_all into LDS (float4, coalesced) — unchanged ----
    {
        const int tot_self = NB * (F / 4);              // 128 float4
        for (int i = tid; i < tot_self; i += NTHREADS) {
            int nb = i / (F / 4);
            int f4 = i % (F / 4);
            if (node0 + nb < N) {
                float4 v = ((const float4*)(x_self + (size_t)(node0 + nb) * F))[f4];
                *(float4*)&xall[nb][0][f4 * 4] = v;
            }
        }
        const int tot_n = NB * K * (F / 4);             // 2048 float4
        for (int i = tid; i < tot_n; i += NTHREADS) {
            int nb  = i / (K * F / 4);
            int rem = i % (K * F / 4);
            int k   = rem / (F / 4);
            int f4  = rem % (F / 4);
            if (node0 + nb < N) {
                float4 v = ((const float4*)(x_neigh + ((size_t)(node0 + nb) * K + k) * F))[f4];
                *(float4*)&xall[nb][k + 1][f4 * 4] = v;
            }
        }
    }
    __syncthreads();

    // ---- Phase 2: logit dots, row-paired; float2 write into transposed attnT ----
    {
        const int p  = tid & 7;          // rows 2p, 2p+1 (0..15)
        const int h  = (tid >> 3) & 7;
        const int nb = tid >> 6;
        const float* av  = a_neigh + h * F;
        const float* xr0 = &xall[nb][2 * p][0];
        const float* xr1 = &xall[nb][2 * p + 1][0];
        float4 s0 = {0.f, 0.f, 0.f, 0.f}, s1 = s0;
        #pragma unroll 8
        for (int f4 = 0; f4 < F / 4; f4++) {
            float4 avv = ((const float4*)av)[f4];
            float4 x0 = *(const float4*)(xr0 + f4 * 4);
            float4 x1 = *(const float4*)(xr1 + f4 * 4);
            s0.x += x0.x * avv.x; s0.y += x0.y * avv.y;
            s0.z += x0.z * avv.z; s0.w += x0.w * avv.w;
            s1.x += x1.x * avv.x; s1.y += x1.y * avv.y;
            s1.z += x1.z * avv.z; s1.w += x1.w * avv.w;
        }
        float2 dots = { (s0.x + s0.y) + (s0.z + s0.w),
                        (s1.x + s1.y) + (s1.z + s1.w) };
        *(float2*)&attnT[nb][h][2 * p] = dots;

        if (tid < 32) {                  // leftover: row 16 (a_neigh) + self row (a_self)
            const int h2  = tid & 7;
            const int nb2 = tid >> 3;
            const float* avn = a_neigh + h2 * F;
            const float* avs = a_self  + h2 * F;
            const float* x16 = &xall[nb2][16][0];
            const float* xs  = &xall[nb2][0][0];
            float4 t0 = {0.f, 0.f, 0.f, 0.f}, t1 = t0;
            #pragma unroll 8
            for (int f4 = 0; f4 < F / 4; f4++) {
                float4 an = ((const float4*)avn)[f4];
                float4 as = ((const float4*)avs)[f4];
                float4 v0 = *(const float4*)(x16 + f4 * 4);
                float4 v1 = *(const float4*)(xs  + f4 * 4);
                t0.x += v0.x * an.x; t0.y += v0.y * an.y;
                t0.z += v0.z * an.z; t0.w += v0.w * an.w;
                t1.x += v1.x * as.x; t1.y += v1.y * as.y;
                t1.z += v1.z * as.z; t1.w += v1.w * as.w;
            }
            attnT[nb2][h2][16] = (t0.x + t0.y) + (t0.z + t0.w);
            self_s[nb2][h2]    = (t1.x + t1.y) + (t1.z + t1.w);
        }
    }
    __syncthreads();

    // ---- Phase 3: add self logit, LeakyReLU, softmax over k — fully in registers ----
    for (int i = tid; i < NB * H; i += NTHREADS) {
        int nb = i >> 3, h = i & 7;
        float sl = self_s[nb][h];
        float4 l0 = *(float4*)&attnT[nb][h][0];
        float4 l1 = *(float4*)&attnT[nb][h][4];
        float4 l2 = *(float4*)&attnT[nb][h][8];
        float4 l3 = *(float4*)&attnT[nb][h][12];
        float  l4 = attnT[nb][h][16];
        #define LRELU(v) { v += sl; v = (v >= 0.f) ? v : NEG_SLOPE * v; }
        LRELU(l0.x) LRELU(l0.y) LRELU(l0.z) LRELU(l0.w)
        LRELU(l1.x) LRELU(l1.y) LRELU(l1.z) LRELU(l1.w)
        LRELU(l2.x) LRELU(l2.y) LRELU(l2.z) LRELU(l2.w)
        LRELU(l3.x) LRELU(l3.y) LRELU(l3.z) LRELU(l3.w)
        LRELU(l4)
        #undef LRELU
        float m01 = fmaxf(fmaxf(fmaxf(l0.x, l0.y), fmaxf(l0.z, l0.w)),
                          fmaxf(fmaxf(l1.x, l1.y), fmaxf(l1.z, l1.w)));
        float m23 = fmaxf(fmaxf(fmaxf(l2.x, l2.y), fmaxf(l2.z, l2.w)),
                          fmaxf(fmaxf(l3.x, l3.y), fmaxf(l3.z, l3.w)));
        float m = fmaxf(fmaxf(m01, m23), l4);
        float s = 0.f;
        #define EXPS(v) { v = __expf(v - m); s += v; }
        EXPS(l0.x) EXPS(l0.y) EXPS(l0.z) EXPS(l0.w)
        EXPS(l1.x) EXPS(l1.y) EXPS(l1.z) EXPS(l1.w)
        EXPS(l2.x) EXPS(l2.y) EXPS(l2.z) EXPS(l2.w)
        EXPS(l3.x) EXPS(l3.y) EXPS(l3.z) EXPS(l3.w)
        EXPS(l4)
        #undef EXPS
        float inv = 1.0f / s;
        l0.x *= inv; l0.y *= inv; l0.z *= inv; l0.w *= inv;
        l1.x *= inv; l1.y *= inv; l1.z *= inv; l1.w *= inv;
        l2.x *= inv; l2.y *= inv; l2.z *= inv; l2.w *= inv;
        l3.x *= inv; l3.y *= inv; l3.z *= inv; l3.w *= inv;
        l4 *= inv;
        *(float4*)&attnT[nb][h][0]  = l0;
        *(float4*)&attnT[nb][h][4]  = l1;
        *(float4*)&attnT[nb][h][8]  = l2;
        *(float4*)&attnT[nb][h][12] = l3;
        attnT[nb][h][16] = l4;
    }
    __syncthreads();

    // ---- Phase 4: y[nb][h][f] = sum_k attnT * x_all. attn reads now b128 (k-blocked). ----
    {
        const int h  = (tid >> 5) & 7;   // 0..7 (2 distinct h per wave -> broadcast-safe)
        const int f4 = tid & 31;         // 0..31
        float4 acc[NB];
        #pragma unroll
        for (int j = 0; j < NB; j++) acc[j] = {0.f, 0.f, 0.f, 0.f};
        #pragma unroll
        for (int kq = 0; kq < 4; kq++) {
            float4 a[NB];
            #pragma unroll
            for (int j = 0; j < NB; j++) a[j] = *(const float4*)&attnT[j][h][kq * 4];
            #pragma unroll
            for (int j = 0; j < NB; j++) {
                float4 x0 = *(const float4*)&xall[j][kq * 4 + 0][f4 * 4];
                float4 x1 = *(const float4*)&xall[j][kq * 4 + 1][f4 * 4];
                float4 x2 = *(const float4*)&xall[j][kq * 4 + 2][f4 * 4];
                float4 x3 = *(const float4*)&xall[j][kq * 4 + 3][f4 * 4];
                acc[j].x += a[j].x * x0.x + a[j].y * x1.x + a[j].z * x2.x + a[j].w * x3.x;
                acc[j].y += a[j].x * x0.y + a[j].y * x1.y + a[j].z * x2.y + a[j].w * x3.y;
                acc[j].z += a[j].x * x0.z + a[j].y * x1.z + a[j].z * x2.z + a[j].w * x3.z;
                acc[j].w += a[j].x * x0.w + a[j].y * x1.w + a[j].z * x2.w + a[j].w * x3.w;
            }
        }
        #pragma unroll
        for (int j = 0; j < NB; j++) {           // k = 16 tail
            float a16 = attnT[j][h][16];
            float4 xv = *(const float4*)&xall[j][16][f4 * 4];
            acc[j].x += a16 * xv.x; acc[j].y += a16 * xv.y;
            acc[j].z += a16 * xv.z; acc[j].w += a16 * xv.w;
        }
        __syncthreads();   // everyone done READING xall
        #pragma unroll
        for (int j = 0; j < NB; j++) {
            *(float4*)&yb[((size_t)j * H + h) * F + f4 * 4] = acc[j];
        }
    }
    __syncthreads();

    // ---- Phase 5: out[nb][h][d] = y[nb][h][:] @ W[h][:][d].
    //      lane = (fg, d4); wave w handles heads w, w+4. float4 W loads + float4 y loads
    //      + explicit next-fb W prefetch in a second register bank (fb fully unrolled):
    //      next iteration's 8 L2 loads fly during the current 128-FMA block. ----
    {
        const int lane = tid & 63;
        const int w    = tid >> 6;          // wave id -> heads w, w+4
        const int fg   = lane >> 4;         // 0..3 f-phase
        const int d4   = lane & 15;         // d = d4*4 .. d4*4+3
        const int h0 = w, h1 = w + 4;
        const float* Wb0 = W + ((size_t)h0 * F) * D + d4 * 4;
        const float* Wb1 = W + ((size_t)h1 * F) * D + d4 * 4;

        float4 acc0[NB], acc1[NB];
        #pragma unroll
        for (int nb = 0; nb < NB; nb++) {
            acc0[nb] = {0.f, 0.f, 0.f, 0.f};
            acc1[nb] = {0.f, 0.f, 0.f, 0.f};
        }

        // preload fb=0 W tiles
        float4 c00 = *(const float4*)(Wb0 + (size_t)(fg * 4 + 0) * D);
        float4 c01 = *(const float4*)(Wb0 + (size_t)(fg * 4 + 1) * D);
        float4 c02 = *(const float4*)(Wb0 + (size_t)(fg * 4 + 2) * D);
        float4 c03 = *(const float4*)(Wb0 + (size_t)(fg * 4 + 3) * D);
        float4 c10 = *(const float4*)(Wb1 + (size_t)(fg * 4 + 0) * D);
        float4 c11 = *(const float4*)(Wb1 + (size_t)(fg * 4 + 1) * D);
        float4 c12 = *(const float4*)(Wb1 + (size_t)(fg * 4 + 2) * D);
        float4 c13 = *(const float4*)(Wb1 + (size_t)(fg * 4 + 3) * D);

        #pragma unroll
        for (int fb = 0; fb < 8; fb++) {
            const int f0n = ((fb + 1) & 7) * 16 + fg * 4;   // wrap: harmless re-load of fb=0
            // issue NEXT fb's W loads (in flight during this fb's FMAs)
            float4 n00 = *(const float4*)(Wb0 + (size_t)(f0n + 0) * D);
            float4 n01 = *(const float4*)(Wb0 + (size_t)(f0n + 1) * D);
            float4 n02 = *(const float4*)(Wb0 + (size_t)(f0n + 2) * D);
            float4 n03 = *(const float4*)(Wb0 + (size_t)(f0n + 3) * D);
            float4 n10 = *(const float4*)(Wb1 + (size_t)(f0n + 0) * D);
            float4 n11 = *(const float4*)(Wb1 + (size_t)(f0n + 1) * D);
            float4 n12 = *(const float4*)(Wb1 + (size_t)(f0n + 2) * D);
            float4 n13 = *(const float4*)(Wb1 + (size_t)(f0n + 3) * D);

            const int f0 = fb * 16 + fg * 4;
            #pragma unroll
            for (int nb = 0; nb < NB; nb++) {
                float4 y0 = *(const float4*)&yb[((size_t)nb * H + h0) * F + f0];
                float4 y1 = *(const float4*)&yb[((size_t)nb * H + h1) * F + f0];
                acc0[nb].x += y0.x * c00.x + y0.y * c01.x + y0.z * c02.x + y0.w * c03.x;
                acc0[nb].y += y0.x * c00.y + y0.y * c01.y + y0.z * c02.y + y0.w * c03.y;
                acc0[nb].z += y0.x * c00.z + y0.y * c01.z + y0.z * c02.z + y0.w * c03.z;
                acc0[nb].w += y0.x * c00.w + y0.y * c01.w + y0.z * c02.w + y0.w * c03.w;
                acc1[nb].x += y1.x * c10.x + y1.y * c11.x + y1.z * c12.x + y1.w * c13.x;
                acc1[nb].y += y1.x * c10.y + y1.y * c11.y + y1.z * c12.y + y1.w * c13.y;
                acc1[nb].z += y1.x * c10.z + y1.y * c11.z + y1.z * c12.z + y1.w * c13.z;
                acc1[nb].w += y1.x * c10.w + y1.y * c11.w + y1.z * c12.w + y1.w * c13.w;
            }
            // rotate register banks (renamed away by full unroll)
            c00 = n00; c01 = n01; c02 = n02; c03 = n03;
            c10 = n10; c11 = n11; c12 = n12; c13 = n13;
        }

        // reduce over the 4 fg groups (lanes l, l^16, l^32, l^48 share d4)
        #pragma unroll
        for (int nb = 0; nb < NB; nb++) {
            acc0[nb].x += __shfl_xor(acc0[nb].x, 16); acc0[nb].x += __shfl_xor(acc0[nb].x, 32);
            acc0[nb].y += __shfl_xor(acc0[nb].y, 16); acc0[nb].y += __shfl_xor(acc0[nb].y, 32);
            acc0[nb].z += __shfl_xor(acc0[nb].z, 16); acc0[nb].z += __shfl_xor(acc0[nb].z, 32);
            acc0[nb].w += __shfl_xor(acc0[nb].w, 16); acc0[nb].w += __shfl_xor(acc0[nb].w, 32);
            acc1[nb].x += __shfl_xor(acc1[nb].x, 16); acc1[nb].x += __shfl_xor(acc1[nb].x, 32);
            acc1[nb].y += __shfl_xor(acc1[nb].y, 16); acc1[nb].y += __shfl_xor(acc1[nb].y, 32);
            acc1[nb].z += __shfl_xor(acc1[nb].z, 16); acc1[nb].z += __shfl_xor(acc1[nb].z, 32);
            acc1[nb].w += __shfl_xor(acc1[nb].w, 16); acc1[nb].w += __shfl_xor(acc1[nb].w, 32);
        }

        // each fg group stores node nb == fg (16 lanes x 16B = 256B contiguous per store)
        #pragma unroll
        for (int nb = 0; nb < NB; nb++) {
            if (fg == nb && node0 + nb < N) {
                *(float4*)&out[(size_t)(node0 + nb) * (H * D) + h0 * D + d4 * 4] = acc0[nb];
                *(float4*)&out[(size_t)(node0 + nb) * (H * D) + h1 * D + d4 * 4] = acc1[nb];
            }
        }
    }
}

extern "C" void kernel_launch(void* const* d_in, const int* in_sizes, int n_in,
                              void* d_out, int out_size, void* d_ws, size_t ws_size,
                              hipStream_t stream) {
    const float* x_self  = (const float*)d_in[0];
    const float* x_neigh = (const float*)d_in[1];
    const float* W       = (const float*)d_in[2];
    const float* a_self  = (const float*)d_in[3];
    const float* a_neigh = (const float*)d_in[4];
    float* out = (float*)d_out;

    const int N = in_sizes[0] / F;                 // 50000
    const int nblocks = (N + NB - 1) / NB;         // 12500
    gat_kernel<<<nblocks, NTHREADS, 0, stream>>>(x_self, x_neigh, W, a_self, a_neigh, out, N);
}

// Round 6
// 790.597 us; speedup vs baseline: 1.8170x; 1.8170x over previous
//
#include <hip/hip_runtime.h>

#define NTHREADS 256
#define NB 4        // nodes per block (N=50000 -> 12500 blocks, no tail)
#define K 16
#define KP1 17
#define F 128
#define H 8
#define D 64
#define FP 132      // padded xall row stride; 2-way max bank alias = free
#define ATP 20      // attnT row stride (17 used), 16B-aligned rows
#define NEG_SLOPE 0.2f

// LDS: xall 4*17*132*4 = 35904 + attnT 4*8*20*4 = 2560 + self 128 = 38592 B -> 4 blocks/CU
// VGPR: __launch_bounds__(256,4). Round-4 phase 5 (proven 383us, register-light, NO explicit
// W double-buffer -- round 5's 16-float4 prefetch spilled to scratch: 2.8 GB of HBM spill
// traffic, dur 1041us). attnT transpose (P2/P3/P4) kept: conflicts 600K->312K, fewer
// LDS issue slots in P4 (68 scalar b32 -> 20 vector reads), P3 in-register.

__global__ __launch_bounds__(NTHREADS, 4) void gat_kernel(
    const float* __restrict__ x_self,   // [N,F]
    const float* __restrict__ x_neigh,  // [N,K,F]
    const float* __restrict__ W,        // [H,F,D]
    const float* __restrict__ a_self,   // [H,F]
    const float* __restrict__ a_neigh,  // [H,F]
    float* __restrict__ out,            // [N,H*D]
    int N)
{
    __shared__ __align__(16) float xall[NB][KP1][FP];   // k=0 is self row; reused as yb after phase 4
    __shared__ __align__(16) float attnT[NB][H][ATP];   // [node][head][k] transposed
    __shared__ float self_s[NB][H];

    float* yb = (float*)xall;   // [NB][H][F] alias (stride F), valid after phase-4 second sync

    const int tid = threadIdx.x;
    const int node0 = blockIdx.x * NB;

    // ---- Phase 1: stage x_all into LDS (float4, coalesced) ----
    {
        const int tot_self = NB * (F / 4);              // 128 float4
        for (int i = tid; i < tot_self; i += NTHREADS) {
            int nb = i / (F / 4);
            int f4 = i % (F / 4);
            if (node0 + nb < N) {
                float4 v = ((const float4*)(x_self + (size_t)(node0 + nb) * F))[f4];
                *(float4*)&xall[nb][0][f4 * 4] = v;
            }
        }
        const int tot_n = NB * K * (F / 4);             // 2048 float4
        for (int i = tid; i < tot_n; i += NTHREADS) {
            int nb  = i / (K * F / 4);
            int rem = i % (K * F / 4);
            int k   = rem / (F / 4);
            int f4  = rem % (F / 4);
            if (node0 + nb < N) {
                float4 v = ((const float4*)(x_neigh + ((size_t)(node0 + nb) * K + k) * F))[f4];
                *(float4*)&xall[nb][k + 1][f4 * 4] = v;
            }
        }
    }
    __syncthreads();

    // ---- Phase 2: logit dots, row-paired; float2 write into transposed attnT ----
    {
        const int p  = tid & 7;          // rows 2p, 2p+1 (0..15)
        const int h  = (tid >> 3) & 7;
        const int nb = tid >> 6;
        const float* av  = a_neigh + h * F;
        const float* xr0 = &xall[nb][2 * p][0];
        const float* xr1 = &xall[nb][2 * p + 1][0];
        float4 s0 = {0.f, 0.f, 0.f, 0.f}, s1 = s0;
        #pragma unroll 8
        for (int f4 = 0; f4 < F / 4; f4++) {
            float4 avv = ((const float4*)av)[f4];
            float4 x0 = *(const float4*)(xr0 + f4 * 4);
            float4 x1 = *(const float4*)(xr1 + f4 * 4);
            s0.x += x0.x * avv.x; s0.y += x0.y * avv.y;
            s0.z += x0.z * avv.z; s0.w += x0.w * avv.w;
            s1.x += x1.x * avv.x; s1.y += x1.y * avv.y;
            s1.z += x1.z * avv.z; s1.w += x1.w * avv.w;
        }
        float2 dots = { (s0.x + s0.y) + (s0.z + s0.w),
                        (s1.x + s1.y) + (s1.z + s1.w) };
        *(float2*)&attnT[nb][h][2 * p] = dots;

        if (tid < 32) {                  // leftover: row 16 (a_neigh) + self row (a_self)
            const int h2  = tid & 7;
            const int nb2 = tid >> 3;
            const float* avn = a_neigh + h2 * F;
            const float* avs = a_self  + h2 * F;
            const float* x16 = &xall[nb2][16][0];
            const float* xs  = &xall[nb2][0][0];
            float4 t0 = {0.f, 0.f, 0.f, 0.f}, t1 = t0;
            #pragma unroll 8
            for (int f4 = 0; f4 < F / 4; f4++) {
                float4 an = ((const float4*)avn)[f4];
                float4 as = ((const float4*)avs)[f4];
                float4 v0 = *(const float4*)(x16 + f4 * 4);
                float4 v1 = *(const float4*)(xs  + f4 * 4);
                t0.x += v0.x * an.x; t0.y += v0.y * an.y;
                t0.z += v0.z * an.z; t0.w += v0.w * an.w;
                t1.x += v1.x * as.x; t1.y += v1.y * as.y;
                t1.z += v1.z * as.z; t1.w += v1.w * as.w;
            }
            attnT[nb2][h2][16] = (t0.x + t0.y) + (t0.z + t0.w);
            self_s[nb2][h2]    = (t1.x + t1.y) + (t1.z + t1.w);
        }
    }
    __syncthreads();

    // ---- Phase 3: add self logit, LeakyReLU, softmax over k — fully in registers ----
    for (int i = tid; i < NB * H; i += NTHREADS) {
        int nb = i >> 3, h = i & 7;
        float sl = self_s[nb][h];
        float4 l0 = *(float4*)&attnT[nb][h][0];
        float4 l1 = *(float4*)&attnT[nb][h][4];
        float4 l2 = *(float4*)&attnT[nb][h][8];
        float4 l3 = *(float4*)&attnT[nb][h][12];
        float  l4 = attnT[nb][h][16];
        #define LRELU(v) { v += sl; v = (v >= 0.f) ? v : NEG_SLOPE * v; }
        LRELU(l0.x) LRELU(l0.y) LRELU(l0.z) LRELU(l0.w)
        LRELU(l1.x) LRELU(l1.y) LRELU(l1.z) LRELU(l1.w)
        LRELU(l2.x) LRELU(l2.y) LRELU(l2.z) LRELU(l2.w)
        LRELU(l3.x) LRELU(l3.y) LRELU(l3.z) LRELU(l3.w)
        LRELU(l4)
        #undef LRELU
        float m01 = fmaxf(fmaxf(fmaxf(l0.x, l0.y), fmaxf(l0.z, l0.w)),
                          fmaxf(fmaxf(l1.x, l1.y), fmaxf(l1.z, l1.w)));
        float m23 = fmaxf(fmaxf(fmaxf(l2.x, l2.y), fmaxf(l2.z, l2.w)),
                          fmaxf(fmaxf(l3.x, l3.y), fmaxf(l3.z, l3.w)));
        float m = fmaxf(fmaxf(m01, m23), l4);
        float s = 0.f;
        #define EXPS(v) { v = __expf(v - m); s += v; }
        EXPS(l0.x) EXPS(l0.y) EXPS(l0.z) EXPS(l0.w)
        EXPS(l1.x) EXPS(l1.y) EXPS(l1.z) EXPS(l1.w)
        EXPS(l2.x) EXPS(l2.y) EXPS(l2.z) EXPS(l2.w)
        EXPS(l3.x) EXPS(l3.y) EXPS(l3.z) EXPS(l3.w)
        EXPS(l4)
        #undef EXPS
        float inv = 1.0f / s;
        l0.x *= inv; l0.y *= inv; l0.z *= inv; l0.w *= inv;
        l1.x *= inv; l1.y *= inv; l1.z *= inv; l1.w *= inv;
        l2.x *= inv; l2.y *= inv; l2.z *= inv; l2.w *= inv;
        l3.x *= inv; l3.y *= inv; l3.z *= inv; l3.w *= inv;
        l4 *= inv;
        *(float4*)&attnT[nb][h][0]  = l0;
        *(float4*)&attnT[nb][h][4]  = l1;
        *(float4*)&attnT[nb][h][8]  = l2;
        *(float4*)&attnT[nb][h][12] = l3;
        attnT[nb][h][16] = l4;
    }
    __syncthreads();

    // ---- Phase 4: y[nb][h][f] = sum_k attnT * x_all. attn reads are b128 (k-blocked). ----
    {
        const int h  = (tid >> 5) & 7;   // 0..7 (2 distinct h per wave -> broadcast-safe)
        const int f4 = tid & 31;         // 0..31
        float4 acc[NB];
        #pragma unroll
        for (int j = 0; j < NB; j++) acc[j] = {0.f, 0.f, 0.f, 0.f};
        #pragma unroll
        for (int kq = 0; kq < 4; kq++) {
            float4 a[NB];
            #pragma unroll
            for (int j = 0; j < NB; j++) a[j] = *(const float4*)&attnT[j][h][kq * 4];
            #pragma unroll
            for (int j = 0; j < NB; j++) {
                float4 x0 = *(const float4*)&xall[j][kq * 4 + 0][f4 * 4];
                float4 x1 = *(const float4*)&xall[j][kq * 4 + 1][f4 * 4];
                float4 x2 = *(const float4*)&xall[j][kq * 4 + 2][f4 * 4];
                float4 x3 = *(const float4*)&xall[j][kq * 4 + 3][f4 * 4];
                acc[j].x += a[j].x * x0.x + a[j].y * x1.x + a[j].z * x2.x + a[j].w * x3.x;
                acc[j].y += a[j].x * x0.y + a[j].y * x1.y + a[j].z * x2.y + a[j].w * x3.y;
                acc[j].z += a[j].x * x0.z + a[j].y * x1.z + a[j].z * x2.z + a[j].w * x3.z;
                acc[j].w += a[j].x * x0.w + a[j].y * x1.w + a[j].z * x2.w + a[j].w * x3.w;
            }
        }
        #pragma unroll
        for (int j = 0; j < NB; j++) {           // k = 16 tail
            float a16 = attnT[j][h][16];
            float4 xv = *(const float4*)&xall[j][16][f4 * 4];
            acc[j].x += a16 * xv.x; acc[j].y += a16 * xv.y;
            acc[j].z += a16 * xv.z; acc[j].w += a16 * xv.w;
        }
        __syncthreads();   // everyone done READING xall
        #pragma unroll
        for (int j = 0; j < NB; j++) {
            *(float4*)&yb[((size_t)j * H + h) * F + f4 * 4] = acc[j];
        }
    }
    __syncthreads();

    // ---- Phase 5 (round-4 exact, proven no-spill): out[nb][h][d] = y[nb][h][:] @ W[h][:][d].
    //      lane = (fg, d4): fg = lane>>4 picks f-phase (f = fb*16 + fg*4 + ff),
    //      d4 = lane&15 covers d = 4*d4..+3. Wave w handles heads w and w+4.
    //      Per fb-iter: 8 float4 y LDS reads + 8 float4 W VMEM loads + 128 FMA.
    //      Compiler-scheduled loads (register-light); NO explicit double-buffer. ----
    {
        const int lane = tid & 63;
        const int w    = tid >> 6;          // wave id -> heads w, w+4
        const int fg   = lane >> 4;         // 0..3 f-phase
        const int d4   = lane & 15;         // d = d4*4 .. d4*4+3
        const int h0 = w, h1 = w + 4;
        const float* Wb0 = W + ((size_t)h0 * F) * D + d4 * 4;
        const float* Wb1 = W + ((size_t)h1 * F) * D + d4 * 4;

        float4 acc0[NB], acc1[NB];
        #pragma unroll
        for (int nb = 0; nb < NB; nb++) {
            acc0[nb] = {0.f, 0.f, 0.f, 0.f};
            acc1[nb] = {0.f, 0.f, 0.f, 0.f};
        }

        for (int fb = 0; fb < 8; fb++) {
            const int f0 = fb * 16 + fg * 4;       // this lane's 4 f values: f0..f0+3
            // W loads first (longest latency), 8 float4
            float4 w0[4], w1[4];
            #pragma unroll
            for (int ff = 0; ff < 4; ff++) {
                w0[ff] = *(const float4*)(Wb0 + (size_t)(f0 + ff) * D);
                w1[ff] = *(const float4*)(Wb1 + (size_t)(f0 + ff) * D);
            }
            // y loads, 8 float4 from LDS
            float4 y0[NB], y1[NB];
            #pragma unroll
            for (int nb = 0; nb < NB; nb++) {
                y0[nb] = *(const float4*)&yb[((size_t)nb * H + h0) * F + f0];
                y1[nb] = *(const float4*)&yb[((size_t)nb * H + h1) * F + f0];
            }
            #pragma unroll
            for (int nb = 0; nb < NB; nb++) {
                acc0[nb].x += y0[nb].x * w0[0].x + y0[nb].y * w0[1].x + y0[nb].z * w0[2].x + y0[nb].w * w0[3].x;
                acc0[nb].y += y0[nb].x * w0[0].y + y0[nb].y * w0[1].y + y0[nb].z * w0[2].y + y0[nb].w * w0[3].y;
                acc0[nb].z += y0[nb].x * w0[0].z + y0[nb].y * w0[1].z + y0[nb].z * w0[2].z + y0[nb].w * w0[3].z;
                acc0[nb].w += y0[nb].x * w0[0].w + y0[nb].y * w0[1].w + y0[nb].z * w0[2].w + y0[nb].w * w0[3].w;
                acc1[nb].x += y1[nb].x * w1[0].x + y1[nb].y * w1[1].x + y1[nb].z * w1[2].x + y1[nb].w * w1[3].x;
                acc1[nb].y += y1[nb].x * w1[0].y + y1[nb].y * w1[1].y + y1[nb].z * w1[2].y + y1[nb].w * w1[3].y;
                acc1[nb].z += y1[nb].x * w1[0].z + y1[nb].y * w1[1].z + y1[nb].z * w1[2].z + y1[nb].w * w1[3].z;
                acc1[nb].w += y1[nb].x * w1[0].w + y1[nb].y * w1[1].w + y1[nb].z * w1[2].w + y1[nb].w * w1[3].w;
            }
        }

        // reduce over the 4 fg groups (lanes l, l^16, l^32, l^48 share d4)
        #pragma unroll
        for (int nb = 0; nb < NB; nb++) {
            acc0[nb].x += __shfl_xor(acc0[nb].x, 16); acc0[nb].x += __shfl_xor(acc0[nb].x, 32);
            acc0[nb].y += __shfl_xor(acc0[nb].y, 16); acc0[nb].y += __shfl_xor(acc0[nb].y, 32);
            acc0[nb].z += __shfl_xor(acc0[nb].z, 16); acc0[nb].z += __shfl_xor(acc0[nb].z, 32);
            acc0[nb].w += __shfl_xor(acc0[nb].w, 16); acc0[nb].w += __shfl_xor(acc0[nb].w, 32);
            acc1[nb].x += __shfl_xor(acc1[nb].x, 16); acc1[nb].x += __shfl_xor(acc1[nb].x, 32);
            acc1[nb].y += __shfl_xor(acc1[nb].y, 16); acc1[nb].y += __shfl_xor(acc1[nb].y, 32);
            acc1[nb].z += __shfl_xor(acc1[nb].z, 16); acc1[nb].z += __shfl_xor(acc1[nb].z, 32);
            acc1[nb].w += __shfl_xor(acc1[nb].w, 16); acc1[nb].w += __shfl_xor(acc1[nb].w, 32);
        }

        // each fg group stores node nb == fg (16 lanes x 16B = 256B contiguous per store)
        #pragma unroll
        for (int nb = 0; nb < NB; nb++) {
            if (fg == nb && node0 + nb < N) {
                *(float4*)&out[(size_t)(node0 + nb) * (H * D) + h0 * D + d4 * 4] = acc0[nb];
                *(float4*)&out[(size_t)(node0 + nb) * (H * D) + h1 * D + d4 * 4] = acc1[nb];
            }
        }
    }
}

extern "C" void kernel_launch(void* const* d_in, const int* in_sizes, int n_in,
                              void* d_out, int out_size, void* d_ws, size_t ws_size,
                              hipStream_t stream) {
    const float* x_self  = (const float*)d_in[0];
    const float* x_neigh = (const float*)d_in[1];
    const float* W       = (const float*)d_in[2];
    const float* a_self  = (const float*)d_in[3];
    const float* a_neigh = (const float*)d_in[4];
    float* out = (float*)d_out;

    const int N = in_sizes[0] / F;                 // 50000
    const int nblocks = (N + NB - 1) / NB;         // 12500
    gat_kernel<<<nblocks, NTHREADS, 0, stream>>>(x_self, x_neigh, W, a_self, a_neigh, out, N);
}